// Round 1
// baseline (549.257 us; speedup 1.0000x reference)
//
#include <hip/hip_runtime.h>

#define B_ 32
#define T_ 4096
#define D_ 256
#define A_ 128

// -----------------------------------------------------------------------------
// Kernel 1: score[b,t] = sum_a tanh( h[b,t,:]·W[a,:] + b_w[a] ) * u_w[a]
// Block = 256 threads = 4 waves. Block owns 64 rows of flattened [B*T].
// Wave w owns a-range [w*32, w*32+32); lane l owns row blk*64+l.
// W index is wave-uniform -> all 64 lanes load the same W address (one
// broadcast transaction). acc[] is statically indexed (full unroll).
// -----------------------------------------------------------------------------
__global__ __launch_bounds__(256) void score_kernel(
    const float* __restrict__ h, const float* __restrict__ W,
    const float* __restrict__ bw, const float* __restrict__ uw,
    float* __restrict__ score)
{
    const int tid  = threadIdx.x;
    const int wave = tid >> 6;
    const int lane = tid & 63;
    const int row  = blockIdx.x * 64 + lane;   // flattened (b,t)
    const int aBase = wave * 32;

    float acc[32];
#pragma unroll
    for (int j = 0; j < 32; ++j) acc[j] = 0.f;

    const float* hrow = h + (size_t)row * D_;

    for (int d0 = 0; d0 < D_; d0 += 8) {
        const float4 h0 = *reinterpret_cast<const float4*>(hrow + d0);
        const float4 h1 = *reinterpret_cast<const float4*>(hrow + d0 + 4);
#pragma unroll
        for (int j = 0; j < 32; ++j) {
            const float* wrow = W + (size_t)(aBase + j) * D_ + d0;
            const float4 w0 = *reinterpret_cast<const float4*>(wrow);
            const float4 w1 = *reinterpret_cast<const float4*>(wrow + 4);
            float s = acc[j];
            s = fmaf(h0.x, w0.x, s); s = fmaf(h0.y, w0.y, s);
            s = fmaf(h0.z, w0.z, s); s = fmaf(h0.w, w0.w, s);
            s = fmaf(h1.x, w1.x, s); s = fmaf(h1.y, w1.y, s);
            s = fmaf(h1.z, w1.z, s); s = fmaf(h1.w, w1.w, s);
            acc[j] = s;
        }
    }

    float part = 0.f;
#pragma unroll
    for (int j = 0; j < 32; ++j) {
        float u = tanhf(acc[j] + bw[aBase + j]);
        part = fmaf(u, uw[aBase + j], part);
    }

    __shared__ float partial[4][64];
    partial[wave][lane] = part;
    __syncthreads();
    if (tid < 64) {
        float s = partial[0][tid] + partial[1][tid]
                + partial[2][tid] + partial[3][tid];
        score[(size_t)blockIdx.x * 64 + tid] = s;
    }
}

// -----------------------------------------------------------------------------
// Kernel 2: in-place softmax over T for each batch row. One block per batch.
// -----------------------------------------------------------------------------
__global__ __launch_bounds__(256) void softmax_kernel(float* __restrict__ score)
{
    const int b   = blockIdx.x;
    const int tid = threadIdx.x;
    float* row = score + (size_t)b * T_;

    __shared__ float sbuf[T_];   // 16 KB
    __shared__ float red[256];

    float lmax = -3.0e38f;
    for (int t = tid; t < T_; t += 256) {
        float v = row[t];
        sbuf[t] = v;
        lmax = fmaxf(lmax, v);
    }
    red[tid] = lmax;
    __syncthreads();
    for (int s = 128; s > 0; s >>= 1) {
        if (tid < s) red[tid] = fmaxf(red[tid], red[tid + s]);
        __syncthreads();
    }
    const float m = red[0];
    __syncthreads();

    float lsum = 0.f;
    for (int t = tid; t < T_; t += 256) {
        float e = expf(sbuf[t] - m);
        sbuf[t] = e;
        lsum += e;
    }
    red[tid] = lsum;
    __syncthreads();
    for (int s = 128; s > 0; s >>= 1) {
        if (tid < s) red[tid] += red[tid + s];
        __syncthreads();
    }
    const float inv = 1.f / red[0];
    __syncthreads();

    for (int t = tid; t < T_; t += 256)
        row[t] = sbuf[t] * inv;
}

// -----------------------------------------------------------------------------
// Kernel 3: partial weighted pooling. Grid (64 chunks, 32 batches).
// Block (b, c) accumulates s_part[b][c][d] = sum over 64 t of alpha*h.
// Fixed summation order -> deterministic (no float atomics).
// -----------------------------------------------------------------------------
__global__ __launch_bounds__(256) void pool_partial_kernel(
    const float* __restrict__ h, const float* __restrict__ alpha,
    float* __restrict__ part)
{
    const int b = blockIdx.y;
    const int c = blockIdx.x;          // 0..63, each covers 64 t
    const int d = threadIdx.x;         // 0..255

    const float* hp = h + ((size_t)b * T_ + (size_t)c * 64) * D_ + d;
    const float* ap = alpha + (size_t)b * T_ + (size_t)c * 64;

    float acc = 0.f;
#pragma unroll 8
    for (int t = 0; t < 64; ++t)
        acc = fmaf(ap[t], hp[(size_t)t * D_], acc);

    part[((size_t)b * 64 + c) * D_ + d] = acc;
}

// -----------------------------------------------------------------------------
// Kernel 4: reduce 64 partials -> out[b][d]
// -----------------------------------------------------------------------------
__global__ __launch_bounds__(256) void pool_reduce_kernel(
    const float* __restrict__ part, float* __restrict__ out)
{
    const int b = blockIdx.x;
    const int d = threadIdx.x;
    float acc = 0.f;
#pragma unroll 8
    for (int c = 0; c < 64; ++c)
        acc += part[((size_t)b * 64 + c) * D_ + d];
    out[(size_t)b * D_ + d] = acc;
}

extern "C" void kernel_launch(void* const* d_in, const int* in_sizes, int n_in,
                              void* d_out, int out_size, void* d_ws, size_t ws_size,
                              hipStream_t stream) {
    const float* h  = (const float*)d_in[0];
    const float* W  = (const float*)d_in[1];
    const float* bw = (const float*)d_in[2];
    const float* uw = (const float*)d_in[3];
    float* out = (float*)d_out;

    float* score = (float*)d_ws;                 // B*T floats   = 512 KB
    float* part  = score + (size_t)B_ * T_;      // B*64*D floats = 2 MB

    score_kernel<<<dim3((B_ * T_) / 64), 256, 0, stream>>>(h, W, bw, uw, score);
    softmax_kernel<<<dim3(B_), 256, 0, stream>>>(score);
    pool_partial_kernel<<<dim3(64, B_), 256, 0, stream>>>(h, score, part);
    pool_reduce_kernel<<<dim3(B_), 256, 0, stream>>>(part, out);
}

// Round 2
// 131.956 us; speedup vs baseline: 4.1624x; 4.1624x over previous
//
#include <hip/hip_runtime.h>

#define B_ 32
#define T_ 4096
#define D_ 256
#define A_ 128

typedef __attribute__((ext_vector_type(8))) short bf16x8;
typedef __attribute__((ext_vector_type(4))) float f32x4;

__device__ __forceinline__ ushort f32_to_bf16_rne(float x) {
    uint u = __float_as_uint(x);
    u = (u + 0x7FFFu + ((u >> 16) & 1u)) >> 16;
    return (ushort)u;
}
__device__ __forceinline__ float bf16_bits_to_f32(ushort b) {
    return __uint_as_float(((uint)b) << 16);
}

// -----------------------------------------------------------------------------
// Kernel 0: convert W [A][D] fp32 -> W_hi, W_lo bf16 planes (row-major [A][D]).
// -----------------------------------------------------------------------------
__global__ __launch_bounds__(256) void convert_W_kernel(
    const float* __restrict__ W, ushort* __restrict__ Whi, ushort* __restrict__ Wlo)
{
    const int i = blockIdx.x * 256 + threadIdx.x;   // 0 .. A*D-1 (32768)
    float x = W[i];
    ushort hb = f32_to_bf16_rne(x);
    float rem = x - bf16_bits_to_f32(hb);
    ushort lb = f32_to_bf16_rne(rem);
    Whi[i] = hb;
    Wlo[i] = lb;
}

// -----------------------------------------------------------------------------
// Kernel 1 (MFMA): score[row] = sum_a tanh(h[row,:]·W[a,:] + bw[a]) * uw[a]
// Split-bf16: S ≈ hi·hi + hi·lo + lo·hi.
// Block = 256 thr = 4 waves; wave owns 32 rows (2 row-tiles of 16), all 128 a.
// A-frags loaded per-lane directly from global fp32 + in-register hi/lo split.
// B-frags read from pre-converted bf16 W planes (L2-hot, 128 KB).
// No LDS, no __syncthreads.
// Fragment layout (16x16x32): A row = l&15, k = (l>>4)*8 + i (contig 8);
//                             B col = l&15, same k. D: col=l&15, row=(l>>4)*4+reg.
// -----------------------------------------------------------------------------
__global__ __launch_bounds__(256) void score_mfma_kernel(
    const float* __restrict__ h,
    const ushort* __restrict__ Whi, const ushort* __restrict__ Wlo,
    const float* __restrict__ bw, const float* __restrict__ uw,
    float* __restrict__ score)
{
    const int tid  = threadIdx.x;
    const int wave = tid >> 6;
    const int lane = tid & 63;
    const int l15  = lane & 15;
    const int l4   = lane >> 4;
    const int rowbase = blockIdx.x * 128 + wave * 32;

    f32x4 acc[2][8];
#pragma unroll
    for (int rt = 0; rt < 2; ++rt)
#pragma unroll
        for (int j = 0; j < 8; ++j)
#pragma unroll
            for (int r = 0; r < 4; ++r) acc[rt][j][r] = 0.f;

    for (int kk = 0; kk < 8; ++kk) {
        const int d = kk * 32 + l4 * 8;

        bf16x8 ahi[2], alo[2];
#pragma unroll
        for (int rt = 0; rt < 2; ++rt) {
            const float* hp = h + (size_t)(rowbase + rt * 16 + l15) * D_ + d;
            float xs[8];
            *reinterpret_cast<float4*>(&xs[0]) = *reinterpret_cast<const float4*>(hp);
            *reinterpret_cast<float4*>(&xs[4]) = *reinterpret_cast<const float4*>(hp + 4);
#pragma unroll
            for (int i = 0; i < 8; ++i) {
                ushort hb = f32_to_bf16_rne(xs[i]);
                float rem = xs[i] - bf16_bits_to_f32(hb);
                ushort lb = f32_to_bf16_rne(rem);
                ahi[rt][i] = (short)hb;
                alo[rt][i] = (short)lb;
            }
        }

#pragma unroll
        for (int j = 0; j < 8; ++j) {
            const size_t woff = (size_t)(j * 16 + l15) * D_ + d;
            bf16x8 bhi = *reinterpret_cast<const bf16x8*>(Whi + woff);
            bf16x8 blo = *reinterpret_cast<const bf16x8*>(Wlo + woff);
#pragma unroll
            for (int rt = 0; rt < 2; ++rt) {
                acc[rt][j] = __builtin_amdgcn_mfma_f32_16x16x32_bf16(ahi[rt], bhi, acc[rt][j], 0, 0, 0);
                acc[rt][j] = __builtin_amdgcn_mfma_f32_16x16x32_bf16(alo[rt], bhi, acc[rt][j], 0, 0, 0);
                acc[rt][j] = __builtin_amdgcn_mfma_f32_16x16x32_bf16(ahi[rt], blo, acc[rt][j], 0, 0, 0);
            }
        }
    }

    // Epilogue: lane holds S[rowbase + rt*16 + l4*4 + reg][j*16 + l15]
    float rsum[2][4];
#pragma unroll
    for (int rt = 0; rt < 2; ++rt)
#pragma unroll
        for (int r = 0; r < 4; ++r) rsum[rt][r] = 0.f;

#pragma unroll
    for (int j = 0; j < 8; ++j) {
        const float bwv = bw[j * 16 + l15];
        const float uwv = uw[j * 16 + l15];
#pragma unroll
        for (int rt = 0; rt < 2; ++rt)
#pragma unroll
            for (int r = 0; r < 4; ++r)
                rsum[rt][r] = fmaf(tanhf(acc[rt][j][r] + bwv), uwv, rsum[rt][r]);
    }

    // reduce over the 16 lanes of each l4-group (they cover the 16 a-cols)
#pragma unroll
    for (int rt = 0; rt < 2; ++rt)
#pragma unroll
        for (int r = 0; r < 4; ++r) {
#pragma unroll
            for (int m = 1; m < 16; m <<= 1)
                rsum[rt][r] += __shfl_xor(rsum[rt][r], m, 64);
        }

    if (l15 == 0) {
#pragma unroll
        for (int rt = 0; rt < 2; ++rt)
#pragma unroll
            for (int r = 0; r < 4; ++r)
                score[rowbase + rt * 16 + l4 * 4 + r] = rsum[rt][r];
    }
}

// -----------------------------------------------------------------------------
// Kernel 2: in-place softmax over T for each batch row. One block per batch.
// -----------------------------------------------------------------------------
__global__ __launch_bounds__(256) void softmax_kernel(float* __restrict__ score)
{
    const int b   = blockIdx.x;
    const int tid = threadIdx.x;
    float* row = score + (size_t)b * T_;

    __shared__ float sbuf[T_];
    __shared__ float red[256];

    float lmax = -3.0e38f;
    for (int t = tid; t < T_; t += 256) {
        float v = row[t];
        sbuf[t] = v;
        lmax = fmaxf(lmax, v);
    }
    red[tid] = lmax;
    __syncthreads();
    for (int s = 128; s > 0; s >>= 1) {
        if (tid < s) red[tid] = fmaxf(red[tid], red[tid + s]);
        __syncthreads();
    }
    const float m = red[0];
    __syncthreads();

    float lsum = 0.f;
    for (int t = tid; t < T_; t += 256) {
        float e = expf(sbuf[t] - m);
        sbuf[t] = e;
        lsum += e;
    }
    red[tid] = lsum;
    __syncthreads();
    for (int s = 128; s > 0; s >>= 1) {
        if (tid < s) red[tid] += red[tid + s];
        __syncthreads();
    }
    const float inv = 1.f / red[0];
    __syncthreads();

    for (int t = tid; t < T_; t += 256)
        row[t] = sbuf[t] * inv;
}

// -----------------------------------------------------------------------------
// Kernel 3: partial weighted pooling. Grid (64 chunks, 32 batches).
// -----------------------------------------------------------------------------
__global__ __launch_bounds__(256) void pool_partial_kernel(
    const float* __restrict__ h, const float* __restrict__ alpha,
    float* __restrict__ part)
{
    const int b = blockIdx.y;
    const int c = blockIdx.x;
    const int d = threadIdx.x;

    const float* hp = h + ((size_t)b * T_ + (size_t)c * 64) * D_ + d;
    const float* ap = alpha + (size_t)b * T_ + (size_t)c * 64;

    float acc = 0.f;
#pragma unroll 8
    for (int t = 0; t < 64; ++t)
        acc = fmaf(ap[t], hp[(size_t)t * D_], acc);

    part[((size_t)b * 64 + c) * D_ + d] = acc;
}

__global__ __launch_bounds__(256) void pool_reduce_kernel(
    const float* __restrict__ part, float* __restrict__ out)
{
    const int b = blockIdx.x;
    const int d = threadIdx.x;
    float acc = 0.f;
#pragma unroll 8
    for (int c = 0; c < 64; ++c)
        acc += part[((size_t)b * 64 + c) * D_ + d];
    out[(size_t)b * D_ + d] = acc;
}

extern "C" void kernel_launch(void* const* d_in, const int* in_sizes, int n_in,
                              void* d_out, int out_size, void* d_ws, size_t ws_size,
                              hipStream_t stream) {
    const float* h  = (const float*)d_in[0];
    const float* W  = (const float*)d_in[1];
    const float* bw = (const float*)d_in[2];
    const float* uw = (const float*)d_in[3];
    float* out = (float*)d_out;

    float*  score = (float*)d_ws;                         // B*T floats   = 512 KB
    ushort* Whi   = (ushort*)(score + (size_t)B_ * T_);   // 64 KB
    ushort* Wlo   = Whi + (size_t)A_ * D_;                // 64 KB
    float*  part  = (float*)(Wlo + (size_t)A_ * D_);      // B*64*D floats = 2 MB

    convert_W_kernel<<<dim3((A_ * D_) / 256), 256, 0, stream>>>(W, Whi, Wlo);
    score_mfma_kernel<<<dim3((B_ * T_) / 128), 256, 0, stream>>>(h, Whi, Wlo, bw, uw, score);
    softmax_kernel<<<dim3(B_), 256, 0, stream>>>(score);
    pool_partial_kernel<<<dim3(64, B_), 256, 0, stream>>>(h, score, part);
    pool_reduce_kernel<<<dim3(B_), 256, 0, stream>>>(part, out);
}

// Round 3
// 122.185 us; speedup vs baseline: 4.4953x; 1.0800x over previous
//
#include <hip/hip_runtime.h>

#define B_ 32
#define T_ 4096
#define D_ 256
#define A_ 128

typedef __attribute__((ext_vector_type(8))) short bf16x8;
typedef __attribute__((ext_vector_type(4))) float f32x4;

typedef __attribute__((address_space(3))) void lds_void_t;
typedef const __attribute__((address_space(1))) void gbl_void_t;

__device__ __forceinline__ ushort f32_to_bf16_rne(float x) {
    uint u = __float_as_uint(x);
    u = (u + 0x7FFFu + ((u >> 16) & 1u)) >> 16;
    return (ushort)u;
}
__device__ __forceinline__ float bf16_bits_to_f32(ushort b) {
    return __uint_as_float(((uint)b) << 16);
}

// -----------------------------------------------------------------------------
// Kernel 0: W [A][D] fp32 -> hi/lo bf16 planes.
// -----------------------------------------------------------------------------
__global__ __launch_bounds__(256) void convert_W_kernel(
    const float* __restrict__ W, ushort* __restrict__ Whi, ushort* __restrict__ Wlo)
{
    const int i = blockIdx.x * 256 + threadIdx.x;
    float x = W[i];
    ushort hb = f32_to_bf16_rne(x);
    float rem = x - bf16_bits_to_f32(hb);
    Whi[i] = hb;
    Wlo[i] = f32_to_bf16_rne(rem);
}

// -----------------------------------------------------------------------------
// Kernel 1: score via split-bf16 MFMA, global_load_lds-staged h, double-buffered,
// barrier-free (each wave owns its 32-row LDS slice), counted vmcnt(4).
// LDS tile [128 rows][32 f32] with 16B-slot XOR swizzle: slot' = slot ^ (row&7).
// Staging rows step by 8 => (row&7) is invariant across the 4 stage insts.
// -----------------------------------------------------------------------------
__global__ __launch_bounds__(256) void score_mfma_kernel(
    const float* __restrict__ h,
    const ushort* __restrict__ Whi, const ushort* __restrict__ Wlo,
    const float* __restrict__ bw, const float* __restrict__ uw,
    float* __restrict__ score)
{
    __shared__ float tile[2][128 * 32];   // 2 x 16 KB

    const int tid  = threadIdx.x;
    const int w    = tid >> 6;
    const int lane = tid & 63;
    const int l15  = lane & 15;
    const int l4   = lane >> 4;
    const size_t rowblk = (size_t)blockIdx.x * 128;

    // ---- staging geometry (constant per lane) ----
    // inst i: LDS bytes [w*4096 + i*1024 + lane*16]; decodes to
    // row = w*32 + i*8 + lane/8, slot = lane%8 (linear dest).
    // Source must hold slot^(row&7) so that the swizzled READ sees the right data.
    const int srow  = w * 32 + (lane >> 3);
    const int s_src = (lane & 7) ^ (srow & 7);
    const float* gbase = h + (rowblk + srow) * D_ + s_src * 4;
    char* ldsbase = (char*)&tile[0][0];

#define STAGE(buf, st)                                                          \
    {                                                                           \
        const float* gs = gbase + (st) * 32;                                    \
        char* lb = ldsbase + (buf) * 16384 + w * 4096;                          \
        __builtin_amdgcn_global_load_lds((gbl_void_t*)(gs),            (lds_void_t*)(lb),        16, 0, 0); \
        __builtin_amdgcn_global_load_lds((gbl_void_t*)(gs + 8  * D_),  (lds_void_t*)(lb + 1024), 16, 0, 0); \
        __builtin_amdgcn_global_load_lds((gbl_void_t*)(gs + 16 * D_),  (lds_void_t*)(lb + 2048), 16, 0, 0); \
        __builtin_amdgcn_global_load_lds((gbl_void_t*)(gs + 24 * D_),  (lds_void_t*)(lb + 3072), 16, 0, 0); \
    }

    f32x4 acc[2][8];
#pragma unroll
    for (int rt = 0; rt < 2; ++rt)
#pragma unroll
        for (int j = 0; j < 8; ++j)
#pragma unroll
            for (int r = 0; r < 4; ++r) acc[rt][j][r] = 0.f;

    // precomputed swizzled read offsets (constant per lane, per rt)
    int rdoff[2][2];
#pragma unroll
    for (int rt = 0; rt < 2; ++rt) {
        const int trow = w * 32 + rt * 16 + l15;
        const int rsw  = trow & 7;
        rdoff[rt][0] = trow * 128 + (((l4 << 1) + 0) ^ rsw) * 16;
        rdoff[rt][1] = trow * 128 + (((l4 << 1) + 1) ^ rsw) * 16;
    }

    STAGE(0, 0);   // prologue

#pragma unroll
    for (int st = 0; st < 8; ++st) {
        const int cur = st & 1;
        if (st < 7) {
            STAGE(cur ^ 1, st + 1);
            asm volatile("s_waitcnt vmcnt(4)" ::: "memory");  // tile st ready, st+1 in flight
        } else {
            asm volatile("s_waitcnt vmcnt(0)" ::: "memory");
        }
        __builtin_amdgcn_sched_barrier(0);

        // LDS -> regs -> split bf16
        bf16x8 ahi[2], alo[2];
#pragma unroll
        for (int rt = 0; rt < 2; ++rt) {
            const char* lb = ldsbase + cur * 16384;
            float4 x0 = *(const float4*)(lb + rdoff[rt][0]);
            float4 x1 = *(const float4*)(lb + rdoff[rt][1]);
            float xs[8] = {x0.x, x0.y, x0.z, x0.w, x1.x, x1.y, x1.z, x1.w};
#pragma unroll
            for (int i = 0; i < 8; ++i) {
                ushort hb = f32_to_bf16_rne(xs[i]);
                float rem = xs[i] - bf16_bits_to_f32(hb);
                ahi[rt][i] = (short)hb;
                alo[rt][i] = (short)f32_to_bf16_rne(rem);
            }
        }

        const int kb = st * 32 + l4 * 8;
#pragma unroll
        for (int j = 0; j < 8; ++j) {
            const size_t woff = (size_t)(j * 16 + l15) * D_ + kb;
            bf16x8 bhi = *reinterpret_cast<const bf16x8*>(Whi + woff);
            bf16x8 blo = *reinterpret_cast<const bf16x8*>(Wlo + woff);
#pragma unroll
            for (int rt = 0; rt < 2; ++rt) {
                acc[rt][j] = __builtin_amdgcn_mfma_f32_16x16x32_bf16(ahi[rt], bhi, acc[rt][j], 0, 0, 0);
                acc[rt][j] = __builtin_amdgcn_mfma_f32_16x16x32_bf16(alo[rt], bhi, acc[rt][j], 0, 0, 0);
                acc[rt][j] = __builtin_amdgcn_mfma_f32_16x16x32_bf16(ahi[rt], blo, acc[rt][j], 0, 0, 0);
            }
        }
    }
#undef STAGE

    // ---- epilogue: tanh + dot(u_w) + 16-lane reduce ----
    float rsum[2][4];
#pragma unroll
    for (int rt = 0; rt < 2; ++rt)
#pragma unroll
        for (int r = 0; r < 4; ++r) rsum[rt][r] = 0.f;

#pragma unroll
    for (int j = 0; j < 8; ++j) {
        const float bwv = bw[j * 16 + l15];
        const float uwv = uw[j * 16 + l15];
#pragma unroll
        for (int rt = 0; rt < 2; ++rt)
#pragma unroll
            for (int r = 0; r < 4; ++r)
                rsum[rt][r] = fmaf(tanhf(acc[rt][j][r] + bwv), uwv, rsum[rt][r]);
    }

#pragma unroll
    for (int rt = 0; rt < 2; ++rt)
#pragma unroll
        for (int r = 0; r < 4; ++r) {
#pragma unroll
            for (int m = 1; m < 16; m <<= 1)
                rsum[rt][r] += __shfl_xor(rsum[rt][r], m, 64);
        }

    if (l15 == 0) {
        const int rowbase = (int)rowblk + w * 32;
#pragma unroll
        for (int rt = 0; rt < 2; ++rt)
#pragma unroll
            for (int r = 0; r < 4; ++r)
                score[rowbase + rt * 16 + l4 * 4 + r] = rsum[rt][r];
    }
}

// -----------------------------------------------------------------------------
// Kernel 2: in-place softmax over T per batch.
// -----------------------------------------------------------------------------
__global__ __launch_bounds__(256) void softmax_kernel(float* __restrict__ score)
{
    const int b   = blockIdx.x;
    const int tid = threadIdx.x;
    float* row = score + (size_t)b * T_;

    __shared__ float sbuf[T_];
    __shared__ float red[256];

    float lmax = -3.0e38f;
    for (int t = tid; t < T_; t += 256) {
        float v = row[t];
        sbuf[t] = v;
        lmax = fmaxf(lmax, v);
    }
    red[tid] = lmax;
    __syncthreads();
    for (int s = 128; s > 0; s >>= 1) {
        if (tid < s) red[tid] = fmaxf(red[tid], red[tid + s]);
        __syncthreads();
    }
    const float m = red[0];
    __syncthreads();

    float lsum = 0.f;
    for (int t = tid; t < T_; t += 256) {
        float e = expf(sbuf[t] - m);
        sbuf[t] = e;
        lsum += e;
    }
    red[tid] = lsum;
    __syncthreads();
    for (int s = 128; s > 0; s >>= 1) {
        if (tid < s) red[tid] += red[tid + s];
        __syncthreads();
    }
    const float inv = 1.f / red[0];
    __syncthreads();

    for (int t = tid; t < T_; t += 256)
        row[t] = sbuf[t] * inv;
}

// -----------------------------------------------------------------------------
// Kernel 3/4: weighted pooling (partials, then reduce).
// -----------------------------------------------------------------------------
__global__ __launch_bounds__(256) void pool_partial_kernel(
    const float* __restrict__ h, const float* __restrict__ alpha,
    float* __restrict__ part)
{
    const int b = blockIdx.y;
    const int c = blockIdx.x;
    const int d = threadIdx.x;

    const float* hp = h + ((size_t)b * T_ + (size_t)c * 64) * D_ + d;
    const float* ap = alpha + (size_t)b * T_ + (size_t)c * 64;

    float acc = 0.f;
#pragma unroll 8
    for (int t = 0; t < 64; ++t)
        acc = fmaf(ap[t], hp[(size_t)t * D_], acc);

    part[((size_t)b * 64 + c) * D_ + d] = acc;
}

__global__ __launch_bounds__(256) void pool_reduce_kernel(
    const float* __restrict__ part, float* __restrict__ out)
{
    const int b = blockIdx.x;
    const int d = threadIdx.x;
    float acc = 0.f;
#pragma unroll 8
    for (int c = 0; c < 64; ++c)
        acc += part[((size_t)b * 64 + c) * D_ + d];
    out[(size_t)b * D_ + d] = acc;
}

extern "C" void kernel_launch(void* const* d_in, const int* in_sizes, int n_in,
                              void* d_out, int out_size, void* d_ws, size_t ws_size,
                              hipStream_t stream) {
    const float* h  = (const float*)d_in[0];
    const float* W  = (const float*)d_in[1];
    const float* bw = (const float*)d_in[2];
    const float* uw = (const float*)d_in[3];
    float* out = (float*)d_out;

    float*  score = (float*)d_ws;                         // 512 KB
    ushort* Whi   = (ushort*)(score + (size_t)B_ * T_);   // 64 KB
    ushort* Wlo   = Whi + (size_t)A_ * D_;                // 64 KB
    float*  part  = (float*)(Wlo + (size_t)A_ * D_);      // 2 MB

    convert_W_kernel<<<dim3((A_ * D_) / 256), 256, 0, stream>>>(W, Whi, Wlo);
    score_mfma_kernel<<<dim3((B_ * T_) / 128), 256, 0, stream>>>(h, Whi, Wlo, bw, uw, score);
    softmax_kernel<<<dim3(B_), 256, 0, stream>>>(score);
    pool_partial_kernel<<<dim3(64, B_), 256, 0, stream>>>(h, score, part);
    pool_reduce_kernel<<<dim3(B_), 256, 0, stream>>>(part, out);
}